// Round 13
// baseline (95.488 us; speedup 1.0000x reference)
//
#include <hip/hip_runtime.h>
#include <hip/hip_bf16.h>
#include <stdint.h>

#define S_TOK 3072
#define E_DIM 1280
#define H_NUM 20
#define D_HEAD 64
#define NSEG 16

typedef __attribute__((ext_vector_type(8))) short short8;
typedef __attribute__((ext_vector_type(4))) float f32x4;

__device__ __forceinline__ unsigned short f2bf(float f){
  union { float f; unsigned int i; } u; u.f = f;
  unsigned int r = u.i + 0x7FFFu + ((u.i >> 16) & 1u);
  return (unsigned short)(r >> 16);
}

__device__ __forceinline__ void gload_lds16(const void* g, void* l){
  __builtin_amdgcn_global_load_lds((__attribute__((address_space(1))) void*)(g),
                                   (__attribute__((address_space(3))) void*)(l), 16, 0, 0);
}

// -------- f32 -> bf16 conversions for hs + Wq/Wk/Wv (Wo fused into attn) --------
__global__ void cvt_all(const float* __restrict__ hs,
                        const float* __restrict__ w0, const float* __restrict__ w1,
                        const float* __restrict__ w2,
                        unsigned short* __restrict__ hsb,
                        unsigned short* __restrict__ dqkv,
                        int nHS4, int nW4){
  int i = blockIdx.x * blockDim.x + threadIdx.x;
  const float* src;
  unsigned short* dst;
  size_t sj, dj;
  if (i < nHS4){
    src = hs; dst = hsb; sj = i; dj = i;
  } else {
    int t = i - nHS4;
    int w = t / nW4;
    if (w >= 3) return;
    int j = t - w * nW4;
    src = (w == 0) ? w0 : (w == 1) ? w1 : w2;
    sj = j;
    dst = dqkv; dj = (size_t)w * nW4 + j;
  }
  float4 v = reinterpret_cast<const float4*>(src)[sj];
  ushort4 o;
  o.x = f2bf(v.x); o.y = f2bf(v.y); o.z = f2bf(v.z); o.w = f2bf(v.w);
  reinterpret_cast<ushort4*>(dst)[dj] = o;
}

// ------------- m201-faithful 8-phase GEMM: C = A[M,K] @ B[N,K]^T -------------
// BK=64, half-tiles {A0,A1,B0,B1} of HR x 64, double buffered. 4 phases/tile
// (8 per 2 tiles), each phase = one C-quadrant: {ds_read subtile || stage one
// half-tile -> barrier -> lgkmcnt(0) -> 16 MFMA (setprio) -> barrier}.
// vmcnt(6) ONCE per tile (FIFO: forcing oldest load completes tile t fully;
// 3 half-tiles stay in flight). Prologue 7 half-tiles + vmcnt(6); epilogue
// drains 4 -> 2 -> 0 (peeled last tile). Stage targets verified dead:
// each region's last reader phase ends with a barrier before the stage issues.
// MODE 0: BM=256, 8 waves (2x4), scatter q/k/v bf16.  MODE 1: BM=128, 4 waves.
template<int MODE>
__global__ __launch_bounds__(MODE==0?512:256, MODE==0?2:2) void gemm_ph(
    const unsigned short* __restrict__ A,
    const unsigned short* __restrict__ Bp,
    const float* __restrict__ bias0,
    const float* __restrict__ bias1,
    unsigned short* __restrict__ Oq,
    unsigned short* __restrict__ Ok,
    unsigned short* __restrict__ Ov,
    float* __restrict__ Of,
    int M, int N, int K)
{
  constexpr int BM    = MODE==0 ? 256 : 128;
  constexpr int BLOCK = MODE==0 ? 512 : 256;
  constexpr int HR    = BM/2;
  constexpr int HS    = HR*64;            // shorts per half-tile
  constexpr int MR2   = MODE==0 ? 4 : 2;  // m-frags per quadrant

  __shared__ __align__(16) unsigned short SH[8*HS];  // 2 dbuf x {A0,A1,B0,B1}

  // XCD-aware bijective remap (m204), then 4x5 supertile decomposition
  const int nwg = gridDim.x;
  const int xcd = blockIdx.x & 7, ix = blockIdx.x >> 3;
  const int qq = nwg >> 3, rr8 = nwg & 7;
  const int wg = (xcd < rr8 ? xcd*(qq+1) : rr8*(qq+1) + (xcd-rr8)*qq) + ix;
  const int nbn = N / BM;
  const int sgn = nbn / 5;
  const int st = wg / 20, ii = wg % 20;
  const int bm = (st / sgn) * 4 + ii / 5;
  const int bn = (st % sgn) * 5 + ii % 5;
  const int row0 = bm * BM, col0 = bn * BM;

  const int tid  = threadIdx.x;
  const int lane = tid & 63;
  const int w    = tid >> 6;
  const int wm   = MODE==0 ? (w >> 2) : (w >> 1);
  const int wn   = MODE==0 ? (w & 3) : (w & 1);

  const f32x4 fz = {0.f, 0.f, 0.f, 0.f};
  f32x4 acc[4][MR2][2];
#pragma unroll
  for (int qd = 0; qd < 4; ++qd)
#pragma unroll
    for (int m = 0; m < MR2; ++m)
#pragma unroll
      for (int n = 0; n < 2; ++n) acc[qd][m][n] = fz;

  // per-thread staging constants: half-tile = HR*8 slots = 2*BLOCK -> 2/thread
  const int s1 = tid, s2 = BLOCK + tid;
  const int r1 = s1 >> 3, ks1 = (s1 & 7) ^ (r1 & 7);
  const int r2 = s2 >> 3, ks2 = (s2 & 7) ^ (r2 & 7);

  auto stA = [&](int h, int t){
    unsigned short* d = SH + ((t & 1) * 4 + h) * HS;
    const unsigned short* g = A + (size_t)(row0 + h*HR) * K + (t << 6);
    gload_lds16(g + (size_t)r1*K + ks1*8, d + s1*8);
    gload_lds16(g + (size_t)r2*K + ks2*8, d + s2*8);
  };
  auto stB = [&](int h, int t){
    unsigned short* d = SH + ((t & 1) * 4 + 2 + h) * HS;
    const unsigned short* g = Bp + (size_t)(col0 + h*HR) * K + (t << 6);
    gload_lds16(g + (size_t)r1*K + ks1*8, d + s1*8);
    gload_lds16(g + (size_t)r2*K + ks2*8, d + s2*8);
  };

  short8 af[MR2][2], bf0[2][2], bf1[2][2];
  auto RA = [&](int mh, int db){
    const unsigned short* Ah = SH + (db*4 + mh)*HS;
#pragma unroll
    for (int m = 0; m < MR2; ++m){
      int ra = wm*(HR/2) + m*16 + (lane & 15);
#pragma unroll
      for (int kk = 0; kk < 2; ++kk){
        int sl = kk*4 + (lane >> 4);
        af[m][kk] = *reinterpret_cast<const short8*>(&Ah[ra*64 + ((sl ^ (ra & 7)))*8]);
      }
    }
  };
  auto RB = [&](int nh, int db, short8 (*bf)[2]){
    const unsigned short* Bh = SH + (db*4 + 2 + nh)*HS;
#pragma unroll
    for (int n = 0; n < 2; ++n){
      int rb = wn*32 + n*16 + (lane & 15);
#pragma unroll
      for (int kk = 0; kk < 2; ++kk){
        int sl = kk*4 + (lane >> 4);
        bf[n][kk] = *reinterpret_cast<const short8*>(&Bh[rb*64 + ((sl ^ (rb & 7)))*8]);
      }
    }
  };

#define MF_Q(QD, BF)                                                          \
  do {                                                                        \
    __builtin_amdgcn_s_setprio(1);                                            \
    _Pragma("unroll")                                                         \
    for (int kk = 0; kk < 2; ++kk)                                            \
      _Pragma("unroll")                                                       \
      for (int m = 0; m < MR2; ++m)                                           \
        _Pragma("unroll")                                                     \
        for (int n = 0; n < 2; ++n)                                           \
          acc[QD][m][n] = __builtin_amdgcn_mfma_f32_16x16x32_bf16(            \
              af[m][kk], BF[n][kk], acc[QD][m][n], 0, 0, 0);                  \
    __builtin_amdgcn_s_setprio(0);                                            \
  } while (0)

#define LGKM0 do { asm volatile("s_waitcnt lgkmcnt(0)" ::: "memory");         \
                   __builtin_amdgcn_sched_barrier(0); } while (0)
#define BAR   __builtin_amdgcn_s_barrier()

  const int nk = K >> 6;                 // 20
  // prologue: tile0 full + tile1's A0,B0,B1 = 7 half-tiles; vmcnt(6) -> tile0 ready
  stA(0,0); stB(0,0); stB(1,0); stA(1,0);
  stA(0,1); stB(0,1); stB(1,1);
  asm volatile("s_waitcnt vmcnt(6)" ::: "memory");
  BAR;

  for (int t = 0; t < nk - 1; ++t){
    const int db = t & 1;
    const bool f2 = (t + 2 < nk);
    // ph1: quadrant (0,0) — 12 ds_reads
    RA(0, db); RB(0, db, bf0);
    stA(1, t+1);
    BAR; LGKM0; MF_Q(0, bf0); BAR;
    // ph2: quadrant (0,1)
    RB(1, db, bf1);
    if (f2) stA(0, t+2);
    BAR; LGKM0; MF_Q(1, bf1); BAR;
    // ph3: quadrant (1,1)
    RA(1, db);
    if (f2) stB(0, t+2);
    BAR; LGKM0; MF_Q(2, bf1); BAR;
    // ph4: quadrant (1,0) — register-only
    if (f2) stB(1, t+2);
    BAR; MF_Q(3, bf0);
    if (f2) asm volatile("s_waitcnt vmcnt(6)" ::: "memory");
    else    asm volatile("s_waitcnt vmcnt(4)" ::: "memory");
    BAR;
  }
  { // peeled last tile: drain 4 -> 2 -> 0
    const int db = (nk - 1) & 1;
    RA(0, db); RB(0, db, bf0);
    BAR; LGKM0; MF_Q(0, bf0);
    asm volatile("s_waitcnt vmcnt(2)" ::: "memory");
    BAR;
    RB(1, db, bf1);
    BAR; LGKM0; MF_Q(1, bf1);
    asm volatile("s_waitcnt vmcnt(0)" ::: "memory");
    BAR;
    RA(1, db);
    BAR; LGKM0; MF_Q(2, bf1); BAR;
    MF_Q(3, bf0);
  }
  __syncthreads();   // all LDS reads complete before epilogue reuses SH

  if (MODE == 0){
    // coalesced scatter epilogue: two 128-row phases staged in LDS
    unsigned short* Cs = SH;
    const int CSTR = 264;                  // 128 x 264 = 33792 shorts <= 65536
    const int mat = col0 / E_DIM;          // tile-uniform (1280 % 256 == 0)
    const int cc0 = col0 - mat * E_DIM;
    unsigned short* dst = (mat == 0) ? Oq : ((mat == 1) ? Ok : Ov);
    float bb[2][2];
#pragma unroll
    for (int nh = 0; nh < 2; ++nh)
#pragma unroll
      for (int n = 0; n < 2; ++n){
        int cc = cc0 + nh*128 + wn*32 + n*16 + (lane & 15);
        bb[nh][n] = (mat == 0) ? bias0[cc] : (mat == 2 ? bias1[cc] : 0.0f);
      }
#pragma unroll
    for (int ph = 0; ph < 2; ++ph){
#pragma unroll
      for (int q2i = 0; q2i < 2; ++q2i){
        const int qd = ph*2 + q2i;
        const int nh = (qd >> 1) ^ (qd & 1);
#pragma unroll
        for (int m = 0; m < MR2; ++m)
#pragma unroll
          for (int n = 0; n < 2; ++n)
#pragma unroll
            for (int j = 0; j < 4; ++j){
              int rr = wm*64 + m*16 + (lane >> 4)*4 + j;        // 0..127
              int c  = nh*128 + wn*32 + n*16 + (lane & 15);     // 0..255
              Cs[rr * CSTR + c] = f2bf(acc[qd][m][n][j] + bb[nh][n]);
            }
      }
      __syncthreads();
#pragma unroll
      for (int i = 0; i < 8; ++i){
        int tk  = i * 512 + tid;        // 4096 tasks = 4 head-panels x 128r x 8sl
        int p   = tk >> 10;
        int idx = tk & 1023;
        int rr  = idx >> 3, sq = idx & 7;
        short8 vv = *reinterpret_cast<const short8*>(&Cs[rr * CSTR + p * 64 + sq * 8]);
        int gr = row0 + ph * 128 + rr;
        int hh = (cc0 >> 6) + p;
        *reinterpret_cast<short8*>(&dst[((size_t)hh * S_TOK + gr) * D_HEAD + sq * 8]) = vv;
      }
      __syncthreads();
    }
  } else {
    float bc[2][2];
#pragma unroll
    for (int nh = 0; nh < 2; ++nh)
#pragma unroll
      for (int n = 0; n < 2; ++n)
        bc[nh][n] = bias0[col0 + nh*64 + wn*32 + n*16 + (lane & 15)];
#pragma unroll
    for (int qd = 0; qd < 4; ++qd){
      const int mh = qd >> 1;
      const int nh = (qd >> 1) ^ (qd & 1);
#pragma unroll
      for (int m = 0; m < MR2; ++m)
#pragma unroll
        for (int n = 0; n < 2; ++n){
          int c = col0 + nh*64 + wn*32 + n*16 + (lane & 15);
#pragma unroll
          for (int j = 0; j < 4; ++j){
            int r = row0 + mh*64 + wm*32 + m*16 + (lane >> 4)*4 + j;
            Of[(size_t)r * E_DIM + c] = acc[qd][m][n][j] + bc[nh][n];
          }
        }
    }
  }
#undef MF_Q
#undef LGKM0
#undef BAR
}

// ---------------- block-diagonal attention (+fused Wo f32->bf16 cvt) ----------------
#define VSTR 200
#define PSTR 72
#define ATTN_BLKS (H_NUM * NSEG * 3)
__global__ __launch_bounds__(256, 3) void attn_kernel(
    const unsigned short* __restrict__ Q,
    const unsigned short* __restrict__ Kb,
    const unsigned short* __restrict__ V,
    const int* __restrict__ cu,
    unsigned short* __restrict__ O,
    const float* __restrict__ Wo,
    unsigned short* __restrict__ wob,
    int nW4)
{
  __shared__ __align__(16) unsigned short Vt[64*VSTR];     // [d][k-row]
  __shared__ __align__(16) unsigned short Pw[4][16][PSTR]; // per-wave scratch

  const int bid  = blockIdx.x;
  if (bid >= ATTN_BLKS){
    int i = (bid - ATTN_BLKS) * 256 + threadIdx.x;
    if (i < nW4){
      float4 v = reinterpret_cast<const float4*>(Wo)[i];
      ushort4 o;
      o.x = f2bf(v.x); o.y = f2bf(v.y); o.z = f2bf(v.z); o.w = f2bf(v.w);
      reinterpret_cast<ushort4*>(wob)[i] = o;
    }
    return;
  }
  const int unit = bid / 3;
  const int third= bid - unit*3;
  const int h    = unit >> 4;
  const int seg  = unit & 15;
  const int s0   = cu[seg];
  const int L    = cu[seg + 1] - s0;
  if (L <= 0) return;

  const int tid  = threadIdx.x;
  const int lane = tid & 63;
  const int w    = tid >> 6;
  const int row0g = third*64 + w*16;

  const unsigned short* qh = Q  + (size_t)h * S_TOK * D_HEAD;
  const unsigned short* kh = Kb + (size_t)h * S_TOK * D_HEAD;
  const unsigned short* vh = V  + (size_t)h * S_TOK * D_HEAD;

#pragma unroll
  for (int i = 0; i < 6; ++i){
    int task = i*256 + tid;            // 1536 tasks = 192 rows x 8 d-groups
    int sr   = task % 192;
    int grp  = task / 192;
    int svr  = s0 + (sr < L ? sr : L - 1);
    short8 vv = *reinterpret_cast<const short8*>(vh + (size_t)svr*64 + grp*8);
#pragma unroll
    for (int j = 0; j < 8; ++j) Vt[(grp*8 + j)*VSTR + sr] = (unsigned short)vv[j];
  }

  short8 qf[2];
#pragma unroll
  for (int kk = 0; kk < 2; ++kk){
    int r  = row0g + (lane & 15);
    int sr = s0 + (r < L ? r : L - 1);
    qf[kk] = *reinterpret_cast<const short8*>(qh + (size_t)sr*64 + kk*32 + (lane >> 4)*8);
  }

  __syncthreads();

  const f32x4 fz = {0.f, 0.f, 0.f, 0.f};
  const float SCL = 0.125f * 1.44269504088896f;

  f32x4 sacc[12];
#pragma unroll
  for (int nt = 0; nt < 12; ++nt) sacc[nt] = fz;

#pragma unroll
  for (int nt = 0; nt < 12; ++nt){
    int rb = nt*16 + (lane & 15);
    int sr = s0 + (rb < L ? rb : L - 1);
    const unsigned short* kr = kh + (size_t)sr*64 + (lane >> 4)*8;
    short8 kf0 = *reinterpret_cast<const short8*>(kr);
    short8 kf1 = *reinterpret_cast<const short8*>(kr + 32);
    sacc[nt] = __builtin_amdgcn_mfma_f32_16x16x32_bf16(qf[0], kf0, sacc[nt], 0, 0, 0);
    sacc[nt] = __builtin_amdgcn_mfma_f32_16x16x32_bf16(qf[1], kf1, sacc[nt], 0, 0, 0);
  }

  float rinv[4];
#pragma unroll
  for (int j = 0; j < 4; ++j){
    float mx = -1e30f;
#pragma unroll
    for (int nt = 0; nt < 12; ++nt){
      int c = nt*16 + (lane & 15);
      float vv = (c < L) ? sacc[nt][j] : -1e30f;
      sacc[nt][j] = vv;
      mx = fmaxf(mx, vv);
    }
    mx = fmaxf(mx, __shfl_xor(mx, 1, 64));
    mx = fmaxf(mx, __shfl_xor(mx, 2, 64));
    mx = fmaxf(mx, __shfl_xor(mx, 4, 64));
    mx = fmaxf(mx, __shfl_xor(mx, 8, 64));
    float sum = 0.f;
#pragma unroll
    for (int nt = 0; nt < 12; ++nt){
      float pp = exp2f((sacc[nt][j] - mx) * SCL);
      sacc[nt][j] = pp;
      sum += pp;
    }
    sum += __shfl_xor(sum, 1, 64);
    sum += __shfl_xor(sum, 2, 64);
    sum += __shfl_xor(sum, 4, 64);
    sum += __shfl_xor(sum, 8, 64);
    rinv[j] = 1.0f / sum;
  }

  f32x4 oacc[4];
#pragma unroll
  for (int nt = 0; nt < 4; ++nt) oacc[nt] = fz;

#pragma unroll
  for (int kk = 0; kk < 6; ++kk){
#pragma unroll
    for (int ntl = 0; ntl < 2; ++ntl){
      int nt = kk*2 + ntl;
#pragma unroll
      for (int j = 0; j < 4; ++j)
        Pw[w][(lane >> 4)*4 + j][ntl*16 + (lane & 15)] = f2bf(sacc[nt][j]);
    }
    short8 pf = *reinterpret_cast<const short8*>(&Pw[w][lane & 15][(lane >> 4)*8]);
#pragma unroll
    for (int nt4 = 0; nt4 < 4; ++nt4){
      int dcol = nt4*16 + (lane & 15);
      short8 vf = *reinterpret_cast<const short8*>(&Vt[dcol*VSTR + kk*32 + (lane >> 4)*8]);
      oacc[nt4] = __builtin_amdgcn_mfma_f32_16x16x32_bf16(pf, vf, oacc[nt4], 0, 0, 0);
    }
  }

#pragma unroll
  for (int nt4 = 0; nt4 < 4; ++nt4)
#pragma unroll
    for (int j = 0; j < 4; ++j)
      Pw[w][(lane >> 4)*4 + j][nt4*16 + (lane & 15)] = f2bf(oacc[nt4][j] * rinv[j]);

  {
    int r = lane >> 2;
    int gr = row0g + r;
    if (gr < L){
#pragma unroll
      for (int part = 0; part < 2; ++part){
        int c0 = (lane & 3)*16 + part*8;
        short8 vv = *reinterpret_cast<const short8*>(&Pw[w][r][c0]);
        *reinterpret_cast<short8*>(&O[(size_t)(s0 + gr) * E_DIM + h*64 + c0]) = vv;
      }
    }
  }
}

// ---------------- host launch ----------------
extern "C" void kernel_launch(void* const* d_in, const int* in_sizes, int n_in,
                              void* d_out, int out_size, void* d_ws, size_t ws_size,
                              hipStream_t stream)
{
  const float* hs = (const float*)d_in[0];
  const float* Wq = (const float*)d_in[1];
  const float* bq = (const float*)d_in[2];
  const float* Wk = (const float*)d_in[3];
  const float* Wv = (const float*)d_in[4];
  const float* bv = (const float*)d_in[5];
  const float* Wo = (const float*)d_in[6];
  const float* bo = (const float*)d_in[7];
  const int*   cu = (const int*)d_in[8];
  float* out = (float*)d_out;

  unsigned short* p = (unsigned short*)d_ws;
  unsigned short* hsb  = p; p += (size_t)S_TOK * E_DIM;
  unsigned short* wqkv = p; p += (size_t)3 * E_DIM * E_DIM;
  unsigned short* wob  = p; p += (size_t)E_DIM * E_DIM;
  unsigned short* qb   = p; p += (size_t)S_TOK * E_DIM;
  unsigned short* kb   = p; p += (size_t)S_TOK * E_DIM;
  unsigned short* vb   = p; p += (size_t)S_TOK * E_DIM;
  unsigned short* aob  = p; p += (size_t)S_TOK * E_DIM;

  const int nHS4 = S_TOK * E_DIM / 4;
  const int nW4  = E_DIM * E_DIM / 4;
  const int nCvt = nHS4 + 3 * nW4;
  cvt_all<<<(nCvt + 255) / 256, 256, 0, stream>>>(hs, Wq, Wk, Wv, hsb, wqkv, nHS4, nW4);

  // QKV: 12 x 15 = 180 blocks of 512
  gemm_ph<0><<<(S_TOK/256) * (3*E_DIM/256), 512, 0, stream>>>(
      hsb, wqkv, bq, bv, qb, kb, vb, nullptr, S_TOK, 3*E_DIM, E_DIM);

  // attention (960 blocks) + fused Wo conversion
  const int cvtWoBlks = (nW4 + 255) / 256;
  attn_kernel<<<ATTN_BLKS + cvtWoBlks, 256, 0, stream>>>(
      qb, kb, vb, cu, aob, Wo, wob, nW4);

  // out-proj: 24 x 10 = 240 blocks of 256
  gemm_ph<1><<<(S_TOK/128) * (E_DIM/128), 256, 0, stream>>>(
      aob, wob, bo, nullptr, nullptr, nullptr, nullptr, out, S_TOK, E_DIM, E_DIM);
}

// Round 14
// 87.193 us; speedup vs baseline: 1.0951x; 1.0951x over previous
//
#include <hip/hip_runtime.h>
#include <hip/hip_bf16.h>
#include <stdint.h>

#define S_TOK 3072
#define E_DIM 1280
#define H_NUM 20
#define D_HEAD 64
#define NSEG 16

typedef __attribute__((ext_vector_type(8))) short short8;
typedef __attribute__((ext_vector_type(4))) float f32x4;

__device__ __forceinline__ unsigned short f2bf(float f){
  union { float f; unsigned int i; } u; u.f = f;
  unsigned int r = u.i + 0x7FFFu + ((u.i >> 16) & 1u);
  return (unsigned short)(r >> 16);
}

__device__ __forceinline__ void gload_lds16(const void* g, void* l){
  __builtin_amdgcn_global_load_lds((__attribute__((address_space(1))) void*)(g),
                                   (__attribute__((address_space(3))) void*)(l), 16, 0, 0);
}

// -------- f32 -> bf16 conversions for hs + Wq/Wk/Wv (Wo fused into attn) --------
__global__ void cvt_all(const float* __restrict__ hs,
                        const float* __restrict__ w0, const float* __restrict__ w1,
                        const float* __restrict__ w2,
                        unsigned short* __restrict__ hsb,
                        unsigned short* __restrict__ dqkv,
                        int nHS4, int nW4){
  int i = blockIdx.x * blockDim.x + threadIdx.x;
  const float* src;
  unsigned short* dst;
  size_t sj, dj;
  if (i < nHS4){
    src = hs; dst = hsb; sj = i; dj = i;
  } else {
    int t = i - nHS4;
    int w = t / nW4;
    if (w >= 3) return;
    int j = t - w * nW4;
    src = (w == 0) ? w0 : (w == 1) ? w1 : w2;
    sj = j;
    dst = dqkv; dj = (size_t)w * nW4 + j;
  }
  float4 v = reinterpret_cast<const float4*>(src)[sj];
  ushort4 o;
  o.x = f2bf(v.x); o.y = f2bf(v.y); o.z = f2bf(v.z); o.w = f2bf(v.w);
  reinterpret_cast<ushort4*>(dst)[dj] = o;
}

#define LGKM0 do { asm volatile("s_waitcnt lgkmcnt(0)" ::: "memory");         \
                   __builtin_amdgcn_sched_barrier(0); } while (0)
#define BAR   __builtin_amdgcn_s_barrier()

// ------------- QKV GEMM: 192x256 tile -> 240 blocks (94% chip fill) -------------
// C = A[3072,1280] @ B[3840,1280]^T, bf16 in, f32 acc. 8 waves (2wm x 4wn),
// wave-tile 96x64, BK=64, dbuf. Stage units per tile: {A full: 3 loads/thr,
// B0: 2, B1: 2} -> 7/thr. Per-phase counted vmcnt (ledger in comments), all
// stages target the OPPOSITE dbuf (race-free by construction). 4 C-quadrants
// (mh,nh) = (0,0),(0,1),(1,1),(1,0); bf0 held q0->q3, bf1 q1->q2, af q2->q3.
__global__ __launch_bounds__(512, 2) void gemm_qkv(
    const unsigned short* __restrict__ A,
    const unsigned short* __restrict__ Bp,
    const float* __restrict__ bias0,   // bq
    const float* __restrict__ bias1,   // bv
    unsigned short* __restrict__ Oq,
    unsigned short* __restrict__ Ok,
    unsigned short* __restrict__ Ov,
    int K)
{
  constexpr int SLOT = (192 + 256) * 64;          // 28672 shorts per dbuf
  __shared__ __align__(16) unsigned short SH[2 * SLOT];

  // XCD-aware bijective remap (nwg=240 % 8 == 0), then 4x5 supertile
  const int nwg = gridDim.x;
  const int xcd = blockIdx.x & 7, ix = blockIdx.x >> 3;
  const int wg = xcd * (nwg >> 3) + ix;
  const int st = wg / 20, ii = wg % 20;           // st: 0..11
  const int bm = (st / 3) * 4 + ii / 5;           // 0..15
  const int bn = (st % 3) * 5 + ii % 5;           // 0..14
  const int row0 = bm * 192, col0 = bn * 256;

  const int tid  = threadIdx.x;
  const int lane = tid & 63;
  const int w    = tid >> 6;
  const int wm   = w >> 2;                        // 0..1
  const int wn   = w & 3;                         // 0..3

  const f32x4 fz = {0.f, 0.f, 0.f, 0.f};
  f32x4 acc[4][3][2];
#pragma unroll
  for (int qd = 0; qd < 4; ++qd)
#pragma unroll
    for (int m = 0; m < 3; ++m)
#pragma unroll
      for (int n = 0; n < 2; ++n) acc[qd][m][n] = fz;

  auto stA = [&](int t){                          // full A: 192x64, 3 loads
    unsigned short* d = SH + (t & 1) * SLOT;
    const unsigned short* g = A + (size_t)row0 * K + (t << 6);
#pragma unroll
    for (int i = 0; i < 3; ++i){
      int s = i * 512 + tid;
      int r = s >> 3, ks = (s & 7) ^ (r & 7);
      gload_lds16(g + (size_t)r * K + ks * 8, d + s * 8);
    }
  };
  auto stB = [&](int h, int t){                   // B half: 128x64, 2 loads
    unsigned short* d = SH + (t & 1) * SLOT + 12288 + h * 8192;
    const unsigned short* g = Bp + (size_t)(col0 + h * 128) * K + (t << 6);
#pragma unroll
    for (int i = 0; i < 2; ++i){
      int s = i * 512 + tid;
      int r = s >> 3, ks = (s & 7) ^ (r & 7);
      gload_lds16(g + (size_t)r * K + ks * 8, d + s * 8);
    }
  };

  short8 af[3][2], bf0[2][2], bf1[2][2];
  auto RA = [&](int mh, int db){
    const unsigned short* Ah = SH + db * SLOT;
#pragma unroll
    for (int m = 0; m < 3; ++m){
      int ra = mh * 96 + wm * 48 + m * 16 + (lane & 15);
#pragma unroll
      for (int kk = 0; kk < 2; ++kk){
        int sl = kk * 4 + (lane >> 4);
        af[m][kk] = *reinterpret_cast<const short8*>(&Ah[ra * 64 + ((sl ^ (ra & 7))) * 8]);
      }
    }
  };
  auto RB = [&](int nh, int db, short8 (*bf)[2]){
    const unsigned short* Bb = SH + db * SLOT + 12288;
#pragma unroll
    for (int n = 0; n < 2; ++n){
      int rb = nh * 128 + wn * 32 + n * 16 + (lane & 15);
#pragma unroll
      for (int kk = 0; kk < 2; ++kk){
        int sl = kk * 4 + (lane >> 4);
        bf[n][kk] = *reinterpret_cast<const short8*>(&Bb[rb * 64 + ((sl ^ (rb & 7))) * 8]);
      }
    }
  };

#define MF_Q(QD, BF)                                                          \
  do {                                                                        \
    __builtin_amdgcn_s_setprio(1);                                            \
    _Pragma("unroll")                                                         \
    for (int kk = 0; kk < 2; ++kk)                                            \
      _Pragma("unroll")                                                       \
      for (int m = 0; m < 3; ++m)                                             \
        _Pragma("unroll")                                                     \
        for (int n = 0; n < 2; ++n)                                           \
          acc[QD][m][n] = __builtin_amdgcn_mfma_f32_16x16x32_bf16(            \
              af[m][kk], BF[n][kk], acc[QD][m][n], 0, 0, 0);                  \
    __builtin_amdgcn_s_setprio(0);                                            \
  } while (0)

  const int nk = K >> 6;                          // 20
  stA(0); stB(0, 0); stB(1, 0);                   // 7 loads out
  for (int t = 0; t < nk; ++t){
    const int db = t & 1;
    const bool nx = (t + 1 < nk);
    // q0 (0,0): entry out=7 {A,B0,B1 of t}; force A+B0 -> leave 2
    asm volatile("s_waitcnt vmcnt(2)" ::: "memory");
    BAR;
    RA(0, db); RB(0, db, bf0);
    if (nx) stA(t + 1);                           // out: 2 -> 5
    LGKM0; MF_Q(0, bf0);
    // q1 (0,1): force B1(t) -> leave A(t+1)=3
    if (nx) asm volatile("s_waitcnt vmcnt(3)" ::: "memory");
    else    asm volatile("s_waitcnt vmcnt(0)" ::: "memory");
    BAR;
    RB(1, db, bf1);
    if (nx) stB(0, t + 1);                        // out: 3 -> 5
    LGKM0; MF_Q(1, bf1);
    // q2 (1,1): A(t) already forced at q0 - no wait
    BAR;
    RA(1, db);
    if (nx) stB(1, t + 1);                        // out: 5 -> 7
    LGKM0; MF_Q(2, bf1);
    // q3 (1,0): register-only (af=half1 from q2, bf0 held from q0)
    BAR;
    MF_Q(3, bf0);
  }
  __syncthreads();

  // ---- coalesced scatter epilogue: two 96-row phases staged in LDS ----
  {
    unsigned short* Cs = SH;
    const int CSTR = 264;                         // 96 x 264 = 25344 <= SLOT
    const int mat = col0 / E_DIM;                 // 1280 % 256 == 0
    const int cc0 = col0 - mat * E_DIM;
    unsigned short* dst = (mat == 0) ? Oq : ((mat == 1) ? Ok : Ov);
    float bb[2][2];
#pragma unroll
    for (int nh = 0; nh < 2; ++nh)
#pragma unroll
      for (int n = 0; n < 2; ++n){
        int cc = cc0 + nh * 128 + wn * 32 + n * 16 + (lane & 15);
        bb[nh][n] = (mat == 0) ? bias0[cc] : (mat == 2 ? bias1[cc] : 0.0f);
      }
#pragma unroll
    for (int ph = 0; ph < 2; ++ph){
#pragma unroll
      for (int q2i = 0; q2i < 2; ++q2i){
        const int qd = ph * 2 + q2i;
        const int nh = (qd >> 1) ^ (qd & 1);
#pragma unroll
        for (int m = 0; m < 3; ++m)
#pragma unroll
          for (int n = 0; n < 2; ++n)
#pragma unroll
            for (int j = 0; j < 4; ++j){
              int rr = wm * 48 + m * 16 + (lane >> 4) * 4 + j;   // 0..95
              int c  = nh * 128 + wn * 32 + n * 16 + (lane & 15);// 0..255
              Cs[rr * CSTR + c] = f2bf(acc[qd][m][n][j] + bb[nh][n]);
            }
      }
      __syncthreads();
#pragma unroll
      for (int i = 0; i < 6; ++i){
        int tk  = i * 512 + tid;        // 3072 tasks = 4 panels x 96r x 8sl
        int p   = tk / 768;
        int idx = tk - p * 768;
        int rr  = idx >> 3, sq = idx & 7;
        short8 vv = *reinterpret_cast<const short8*>(&Cs[rr * CSTR + p * 64 + sq * 8]);
        int gr = row0 + ph * 96 + rr;
        int hh = (cc0 >> 6) + p;
        *reinterpret_cast<short8*>(&dst[((size_t)hh * S_TOK + gr) * D_HEAD + sq * 8]) = vv;
      }
      __syncthreads();
    }
  }
#undef MF_Q
}

// ------------- out-proj GEMM: r12 MODE-1 verbatim (128^2, 4 waves, 240 blocks) -------------
__global__ __launch_bounds__(256, 2) void gemm_out(
    const unsigned short* __restrict__ A,
    const unsigned short* __restrict__ Bp,
    const float* __restrict__ bias0,
    float* __restrict__ Of,
    int K)
{
  constexpr int HS = 64 * 64;                     // shorts per half-tile
  __shared__ __align__(16) unsigned short SH[8 * HS];

  const int nwg = gridDim.x;                      // 240
  const int xcd = blockIdx.x & 7, ix = blockIdx.x >> 3;
  const int wg = xcd * (nwg >> 3) + ix;
  const int st = wg / 20, ii = wg % 20;           // st 0..11
  const int bm = (st / 2) * 4 + ii / 5;           // 0..23
  const int bn = (st % 2) * 5 + ii % 5;           // 0..9
  const int row0 = bm * 128, col0 = bn * 128;

  const int tid  = threadIdx.x;
  const int lane = tid & 63;
  const int w    = tid >> 6;
  const int wm   = w >> 1;
  const int wn   = w & 1;

  const f32x4 fz = {0.f, 0.f, 0.f, 0.f};
  f32x4 acc[4][2][2];
#pragma unroll
  for (int qd = 0; qd < 4; ++qd)
#pragma unroll
    for (int m = 0; m < 2; ++m)
#pragma unroll
      for (int n = 0; n < 2; ++n) acc[qd][m][n] = fz;

  const int s1 = tid, s2 = 256 + tid;
  const int r1 = s1 >> 3, ks1 = (s1 & 7) ^ (r1 & 7);
  const int r2 = s2 >> 3, ks2 = (s2 & 7) ^ (r2 & 7);

  auto stA = [&](int h, int t){
    unsigned short* d = SH + ((t & 1) * 4 + h) * HS;
    const unsigned short* g = A + (size_t)(row0 + h * 64) * K + (t << 6);
    gload_lds16(g + (size_t)r1 * K + ks1 * 8, d + s1 * 8);
    gload_lds16(g + (size_t)r2 * K + ks2 * 8, d + s2 * 8);
  };
  auto stB = [&](int h, int t){
    unsigned short* d = SH + ((t & 1) * 4 + 2 + h) * HS;
    const unsigned short* g = Bp + (size_t)(col0 + h * 64) * K + (t << 6);
    gload_lds16(g + (size_t)r1 * K + ks1 * 8, d + s1 * 8);
    gload_lds16(g + (size_t)r2 * K + ks2 * 8, d + s2 * 8);
  };

  short8 af[2][2], bf0[2][2], bf1[2][2];
  auto RA = [&](int mh, int db){
    const unsigned short* Ah = SH + (db * 4 + mh) * HS;
#pragma unroll
    for (int m = 0; m < 2; ++m){
      int ra = wm * 32 + m * 16 + (lane & 15);
#pragma unroll
      for (int kk = 0; kk < 2; ++kk){
        int sl = kk * 4 + (lane >> 4);
        af[m][kk] = *reinterpret_cast<const short8*>(&Ah[ra * 64 + ((sl ^ (ra & 7))) * 8]);
      }
    }
  };
  auto RB = [&](int nh, int db, short8 (*bf)[2]){
    const unsigned short* Bh = SH + (db * 4 + 2 + nh) * HS;
#pragma unroll
    for (int n = 0; n < 2; ++n){
      int rb = wn * 32 + n * 16 + (lane & 15);
#pragma unroll
      for (int kk = 0; kk < 2; ++kk){
        int sl = kk * 4 + (lane >> 4);
        bf[n][kk] = *reinterpret_cast<const short8*>(&Bh[rb * 64 + ((sl ^ (rb & 7))) * 8]);
      }
    }
  };

#define MF_Q(QD, BF)                                                          \
  do {                                                                        \
    __builtin_amdgcn_s_setprio(1);                                            \
    _Pragma("unroll")                                                         \
    for (int kk = 0; kk < 2; ++kk)                                            \
      _Pragma("unroll")                                                       \
      for (int m = 0; m < 2; ++m)                                             \
        _Pragma("unroll")                                                     \
        for (int n = 0; n < 2; ++n)                                           \
          acc[QD][m][n] = __builtin_amdgcn_mfma_f32_16x16x32_bf16(            \
              af[m][kk], BF[n][kk], acc[QD][m][n], 0, 0, 0);                  \
    __builtin_amdgcn_s_setprio(0);                                            \
  } while (0)

  const int nk = K >> 6;                          // 20
  stA(0, 0); stB(0, 0); stB(1, 0); stA(1, 0);     // 8 loads out
  for (int t = 0; t < nk; ++t){
    const int db = t & 1;
    const bool nx = (t + 1 < nk);
    // q0: force A0+B0(t)
    asm volatile("s_waitcnt vmcnt(4)" ::: "memory");
    BAR;
    RA(0, db); RB(0, db, bf0);
    if (nx) stA(0, t + 1);
    LGKM0; MF_Q(0, bf0);
    // q1: force B1(t)
    if (nx) asm volatile("s_waitcnt vmcnt(4)" ::: "memory");
    else    asm volatile("s_waitcnt vmcnt(2)" ::: "memory");
    BAR;
    RB(1, db, bf1);
    if (nx) stB(0, t + 1);
    LGKM0; MF_Q(1, bf1);
    // q2: force A1(t)
    if (nx) asm volatile("s_waitcnt vmcnt(4)" ::: "memory");
    else    asm volatile("s_waitcnt vmcnt(0)" ::: "memory");
    BAR;
    RA(1, db);
    if (nx) stB(1, t + 1);
    LGKM0; MF_Q(2, bf1);
    // q3: register-only
    BAR;
    if (nx) stA(1, t + 1);
    MF_Q(3, bf0);
  }
  __syncthreads();

  float bc[2][2];
#pragma unroll
  for (int nh = 0; nh < 2; ++nh)
#pragma unroll
    for (int n = 0; n < 2; ++n)
      bc[nh][n] = bias0[col0 + nh * 64 + wn * 32 + n * 16 + (lane & 15)];
#pragma unroll
  for (int qd = 0; qd < 4; ++qd){
    const int mh = qd >> 1;
    const int nh = (qd >> 1) ^ (qd & 1);
#pragma unroll
    for (int m = 0; m < 2; ++m)
#pragma unroll
      for (int n = 0; n < 2; ++n){
        int c = col0 + nh * 64 + wn * 32 + n * 16 + (lane & 15);
#pragma unroll
        for (int j = 0; j < 4; ++j){
          int r = row0 + mh * 64 + wm * 32 + m * 16 + (lane >> 4) * 4 + j;
          Of[(size_t)r * E_DIM + c] = acc[qd][m][n][j] + bc[nh][n];
        }
      }
  }
#undef MF_Q
}

// ---------------- block-diagonal attention (+fused Wo f32->bf16 cvt) ----------------
#define VSTR 200
#define PSTR 72
#define ATTN_BLKS (H_NUM * NSEG * 3)
__global__ __launch_bounds__(256, 3) void attn_kernel(
    const unsigned short* __restrict__ Q,
    const unsigned short* __restrict__ Kb,
    const unsigned short* __restrict__ V,
    const int* __restrict__ cu,
    unsigned short* __restrict__ O,
    const float* __restrict__ Wo,
    unsigned short* __restrict__ wob,
    int nW4)
{
  __shared__ __align__(16) unsigned short Vt[64*VSTR];     // [d][k-row]
  __shared__ __align__(16) unsigned short Pw[4][16][PSTR]; // per-wave scratch

  const int bid  = blockIdx.x;
  if (bid >= ATTN_BLKS){
    int i = (bid - ATTN_BLKS) * 256 + threadIdx.x;
    if (i < nW4){
      float4 v = reinterpret_cast<const float4*>(Wo)[i];
      ushort4 o;
      o.x = f2bf(v.x); o.y = f2bf(v.y); o.z = f2bf(v.z); o.w = f2bf(v.w);
      reinterpret_cast<ushort4*>(wob)[i] = o;
    }
    return;
  }
  const int unit = bid / 3;
  const int third= bid - unit*3;
  const int h    = unit >> 4;
  const int seg  = unit & 15;
  const int s0   = cu[seg];
  const int L    = cu[seg + 1] - s0;
  if (L <= 0) return;

  const int tid  = threadIdx.x;
  const int lane = tid & 63;
  const int w    = tid >> 6;
  const int row0g = third*64 + w*16;

  const unsigned short* qh = Q  + (size_t)h * S_TOK * D_HEAD;
  const unsigned short* kh = Kb + (size_t)h * S_TOK * D_HEAD;
  const unsigned short* vh = V  + (size_t)h * S_TOK * D_HEAD;

#pragma unroll
  for (int i = 0; i < 6; ++i){
    int task = i*256 + tid;            // 1536 tasks = 192 rows x 8 d-groups
    int sr   = task % 192;
    int grp  = task / 192;
    int svr  = s0 + (sr < L ? sr : L - 1);
    short8 vv = *reinterpret_cast<const short8*>(vh + (size_t)svr*64 + grp*8);
#pragma unroll
    for (int j = 0; j < 8; ++j) Vt[(grp*8 + j)*VSTR + sr] = (unsigned short)vv[j];
  }

  short8 qf[2];
#pragma unroll
  for (int kk = 0; kk < 2; ++kk){
    int r  = row0g + (lane & 15);
    int sr = s0 + (r < L ? r : L - 1);
    qf[kk] = *reinterpret_cast<const short8*>(qh + (size_t)sr*64 + kk*32 + (lane >> 4)*8);
  }

  __syncthreads();

  const f32x4 fz = {0.f, 0.f, 0.f, 0.f};
  const float SCL = 0.125f * 1.44269504088896f;

  f32x4 sacc[12];
#pragma unroll
  for (int nt = 0; nt < 12; ++nt) sacc[nt] = fz;

#pragma unroll
  for (int nt = 0; nt < 12; ++nt){
    int rb = nt*16 + (lane & 15);
    int sr = s0 + (rb < L ? rb : L - 1);
    const unsigned short* kr = kh + (size_t)sr*64 + (lane >> 4)*8;
    short8 kf0 = *reinterpret_cast<const short8*>(kr);
    short8 kf1 = *reinterpret_cast<const short8*>(kr + 32);
    sacc[nt] = __builtin_amdgcn_mfma_f32_16x16x32_bf16(qf[0], kf0, sacc[nt], 0, 0, 0);
    sacc[nt] = __builtin_amdgcn_mfma_f32_16x16x32_bf16(qf[1], kf1, sacc[nt], 0, 0, 0);
  }

  float rinv[4];
#pragma unroll
  for (int j = 0; j < 4; ++j){
    float mx = -1e30f;
#pragma unroll
    for (int nt = 0; nt < 12; ++nt){
      int c = nt*16 + (lane & 15);
      float vv = (c < L) ? sacc[nt][j] : -1e30f;
      sacc[nt][j] = vv;
      mx = fmaxf(mx, vv);
    }
    mx = fmaxf(mx, __shfl_xor(mx, 1, 64));
    mx = fmaxf(mx, __shfl_xor(mx, 2, 64));
    mx = fmaxf(mx, __shfl_xor(mx, 4, 64));
    mx = fmaxf(mx, __shfl_xor(mx, 8, 64));
    float sum = 0.f;
#pragma unroll
    for (int nt = 0; nt < 12; ++nt){
      float pp = exp2f((sacc[nt][j] - mx) * SCL);
      sacc[nt][j] = pp;
      sum += pp;
    }
    sum += __shfl_xor(sum, 1, 64);
    sum += __shfl_xor(sum, 2, 64);
    sum += __shfl_xor(sum, 4, 64);
    sum += __shfl_xor(sum, 8, 64);
    rinv[j] = 1.0f / sum;
  }

  f32x4 oacc[4];
#pragma unroll
  for (int nt = 0; nt < 4; ++nt) oacc[nt] = fz;

#pragma unroll
  for (int kk = 0; kk < 6; ++kk){
#pragma unroll
    for (int ntl = 0; ntl < 2; ++ntl){
      int nt = kk*2 + ntl;
#pragma unroll
      for (int j = 0; j < 4; ++j)
        Pw[w][(lane >> 4)*4 + j][ntl*16 + (lane & 15)] = f2bf(sacc[nt][j]);
    }
    short8 pf = *reinterpret_cast<const short8*>(&Pw[w][lane & 15][(lane >> 4)*8]);
#pragma unroll
    for (int nt4 = 0; nt4 < 4; ++nt4){
      int dcol = nt4*16 + (lane & 15);
      short8 vf = *reinterpret_cast<const short8*>(&Vt[dcol*VSTR + kk*32 + (lane >> 4)*8]);
      oacc[nt4] = __builtin_amdgcn_mfma_f32_16x16x32_bf16(pf, vf, oacc[nt4], 0, 0, 0);
    }
  }

#pragma unroll
  for (int nt4 = 0; nt4 < 4; ++nt4)
#pragma unroll
    for (int j = 0; j < 4; ++j)
      Pw[w][(lane >> 4)*4 + j][nt4*16 + (lane & 15)] = f2bf(oacc[nt4][j] * rinv[j]);

  {
    int r = lane >> 2;
    int gr = row0g + r;
    if (gr < L){
#pragma unroll
      for (int part = 0; part < 2; ++part){
        int c0 = (lane & 3)*16 + part*8;
        short8 vv = *reinterpret_cast<const short8*>(&Pw[w][r][c0]);
        *reinterpret_cast<short8*>(&O[(size_t)(s0 + gr) * E_DIM + h*64 + c0]) = vv;
      }
    }
  }
}

// ---------------- host launch ----------------
extern "C" void kernel_launch(void* const* d_in, const int* in_sizes, int n_in,
                              void* d_out, int out_size, void* d_ws, size_t ws_size,
                              hipStream_t stream)
{
  const float* hs = (const float*)d_in[0];
  const float* Wq = (const float*)d_in[1];
  const float* bq = (const float*)d_in[2];
  const float* Wk = (const float*)d_in[3];
  const float* Wv = (const float*)d_in[4];
  const float* bv = (const float*)d_in[5];
  const float* Wo = (const float*)d_in[6];
  const float* bo = (const float*)d_in[7];
  const int*   cu = (const int*)d_in[8];
  float* out = (float*)d_out;

  unsigned short* p = (unsigned short*)d_ws;
  unsigned short* hsb  = p; p += (size_t)S_TOK * E_DIM;
  unsigned short* wqkv = p; p += (size_t)3 * E_DIM * E_DIM;
  unsigned short* wob  = p; p += (size_t)E_DIM * E_DIM;
  unsigned short* qb   = p; p += (size_t)S_TOK * E_DIM;
  unsigned short* kb   = p; p += (size_t)S_TOK * E_DIM;
  unsigned short* vb   = p; p += (size_t)S_TOK * E_DIM;
  unsigned short* aob  = p; p += (size_t)S_TOK * E_DIM;

  const int nHS4 = S_TOK * E_DIM / 4;
  const int nW4  = E_DIM * E_DIM / 4;
  const int nCvt = nHS4 + 3 * nW4;
  cvt_all<<<(nCvt + 255) / 256, 256, 0, stream>>>(hs, Wq, Wk, Wv, hsb, wqkv, nHS4, nW4);

  // QKV: 16 x 15 = 240 blocks of 512 (94% chip fill)
  gemm_qkv<<<(S_TOK/192) * (3*E_DIM/256), 512, 0, stream>>>(
      hsb, wqkv, bq, bv, qb, kb, vb, E_DIM);

  // attention (960 blocks) + fused Wo conversion
  const int cvtWoBlks = (nW4 + 255) / 256;
  attn_kernel<<<ATTN_BLKS + cvtWoBlks, 256, 0, stream>>>(
      qb, kb, vb, cu, aob, Wo, wob, nW4);

  // out-proj: 24 x 10 = 240 blocks of 256
  gemm_out<<<(S_TOK/128) * (E_DIM/128), 256, 0, stream>>>(
      aob, wob, bo, out, E_DIM);
}